// Round 5
// baseline (541.191 us; speedup 1.0000x reference)
//
#include <hip/hip_runtime.h>
#include <cfloat>
#include <cstdint>

#define NROWS 262144
#define KCB 512
#define DD 64

// numpy pairwise_sum for n=64 (8-accumulator pattern), bit-exact, no contraction
// (used only by tiny w2 kernel; main kernel inlines it on named registers)
__device__ __forceinline__ float np_pairwise64_sq(const float* a) {
  float r[8];
#pragma unroll
  for (int j = 0; j < 8; ++j) r[j] = __fmul_rn(a[j], a[j]);
#pragma unroll
  for (int i = 8; i < 64; i += 8) {
#pragma unroll
    for (int j = 0; j < 8; ++j) r[j] = __fadd_rn(r[j], __fmul_rn(a[i + j], a[i + j]));
  }
  return __fadd_rn(__fadd_rn(__fadd_rn(r[0], r[1]), __fadd_rn(r[2], r[3])),
                   __fadd_rn(__fadd_rn(r[4], r[5]), __fadd_rn(r[6], r[7])));
}

// ---------------------------------------- w2[k] = np.sum(w*w, axis=1) bit-exact
__global__ __launch_bounds__(512) void w2_kernel(const float* __restrict__ w,
                                                 float* __restrict__ w2) {
  int k = threadIdx.x;
  float wr[64];
  const float4* w4 = (const float4*)(w + (size_t)k * DD);
#pragma unroll
  for (int q = 0; q < 16; ++q) {
    float4 v = w4[q];
    wr[4 * q + 0] = v.x; wr[4 * q + 1] = v.y;
    wr[4 * q + 2] = v.z; wr[4 * q + 3] = v.w;
  }
  w2[k] = np_pairwise64_sq(wr);
}

// sequential-j FMA over one float4 (exact BLAS accumulation order)
#define DOT16(acc, xa, wv)                  \
  acc = fmaf((xa).x, (wv).x, acc);          \
  acc = fmaf((xa).y, (wv).y, acc);          \
  acc = fmaf((xa).z, (wv).z, acc);          \
  acc = fmaf((xa).w, (wv).w, acc)

// 8-term sequential square-sum (one numpy pairwise accumulator)
#define SQ8(R, A0, A1, A2, A3, A4, A5, A6, A7)  \
  R = __fmul_rn((A0), (A0));                    \
  R = __fadd_rn(R, __fmul_rn((A1), (A1)));      \
  R = __fadd_rn(R, __fmul_rn((A2), (A2)));      \
  R = __fadd_rn(R, __fmul_rn((A3), (A3)));      \
  R = __fadd_rn(R, __fmul_rn((A4), (A4)));      \
  R = __fadd_rn(R, __fmul_rn((A5), (A5)));      \
  R = __fadd_rn(R, __fmul_rn((A6), (A6)));      \
  R = __fadd_rn(R, __fmul_rn((A7), (A7)))

// ------- main: np-fp32-bit-exact dist + argmin(first index) + z_q + counts
__global__ __launch_bounds__(256, 4) void vq_main(const float* __restrict__ x,
                                                  const float* __restrict__ w,
                                                  const float* __restrict__ w2,
                                                  float* __restrict__ zq,
                                                  int* __restrict__ idx,
                                                  int* __restrict__ counts) {
  __shared__ int ilds[256];
  __shared__ int lc[KCB];
  const int tid = threadIdx.x;
  const int n = blockIdx.x * 256 + tid;
  for (int i = tid; i < KCB; i += 256) lc[i] = 0;

  // x row -> 16 NAMED float4 registers (no array, no address-taking: stays in VGPRs)
  const float4* x4 = (const float4*)(x + (size_t)n * DD);
  float4 xv0 = x4[0], xv1 = x4[1], xv2 = x4[2], xv3 = x4[3];
  float4 xv4 = x4[4], xv5 = x4[5], xv6 = x4[6], xv7 = x4[7];
  float4 xv8 = x4[8], xv9 = x4[9], xv10 = x4[10], xv11 = x4[11];
  float4 xv12 = x4[12], xv13 = x4[13], xv14 = x4[14], xv15 = x4[15];

  // x2 = np.sum(x*x) bit-exact: 8 stride-8 accumulators + pairwise combine.
  // element e=4q+c; group j holds e=j,j+8,..: j<4 -> even q comp j; j>=4 -> odd q comp j-4
  float r0, r1, r2, r3, r4, r5, r6, r7;
  SQ8(r0, xv0.x, xv2.x, xv4.x, xv6.x, xv8.x, xv10.x, xv12.x, xv14.x);
  SQ8(r1, xv0.y, xv2.y, xv4.y, xv6.y, xv8.y, xv10.y, xv12.y, xv14.y);
  SQ8(r2, xv0.z, xv2.z, xv4.z, xv6.z, xv8.z, xv10.z, xv12.z, xv14.z);
  SQ8(r3, xv0.w, xv2.w, xv4.w, xv6.w, xv8.w, xv10.w, xv12.w, xv14.w);
  SQ8(r4, xv1.x, xv3.x, xv5.x, xv7.x, xv9.x, xv11.x, xv13.x, xv15.x);
  SQ8(r5, xv1.y, xv3.y, xv5.y, xv7.y, xv9.y, xv11.y, xv13.y, xv15.y);
  SQ8(r6, xv1.z, xv3.z, xv5.z, xv7.z, xv9.z, xv11.z, xv13.z, xv15.z);
  SQ8(r7, xv1.w, xv3.w, xv5.w, xv7.w, xv9.w, xv11.w, xv13.w, xv15.w);
  const float x2n = __fadd_rn(__fadd_rn(__fadd_rn(r0, r1), __fadd_rn(r2, r3)),
                              __fadd_rn(__fadd_rn(r4, r5), __fadd_rn(r6, r7)));

  const float4* w4 = (const float4*)w;
  float bestd = FLT_MAX;
  int besti = 0;
  for (int kt = 0; kt < KCB; kt += 4) {
    // t = x @ w.T : strict sequential FMA over j per codeword; 4 chains interleaved
    const float4* wpa = w4 + (size_t)(kt + 0) * 16;
    const float4* wpb = w4 + (size_t)(kt + 1) * 16;
    const float4* wpc = w4 + (size_t)(kt + 2) * 16;
    const float4* wpd = w4 + (size_t)(kt + 3) * 16;
    float a0 = 0.f, a1 = 0.f, a2 = 0.f, a3 = 0.f;
    float4 wa, wb, wc, wd;
#define KSTEP(Q, XQ)                                        \
    wa = wpa[Q]; wb = wpb[Q]; wc = wpc[Q]; wd = wpd[Q];     \
    DOT16(a0, XQ, wa); DOT16(a1, XQ, wb);                   \
    DOT16(a2, XQ, wc); DOT16(a3, XQ, wd)
    KSTEP(0, xv0);   KSTEP(1, xv1);   KSTEP(2, xv2);   KSTEP(3, xv3);
    KSTEP(4, xv4);   KSTEP(5, xv5);   KSTEP(6, xv6);   KSTEP(7, xv7);
    KSTEP(8, xv8);   KSTEP(9, xv9);   KSTEP(10, xv10); KSTEP(11, xv11);
    KSTEP(12, xv12); KSTEP(13, xv13); KSTEP(14, xv14); KSTEP(15, xv15);
#undef KSTEP
    // dist = fl(fl(x2 - 2t) + w2)  (2t exact; np elementwise order)
    const float* w2p = w2 + kt;
    float d0 = __fadd_rn(__fsub_rn(x2n, 2.0f * a0), w2p[0]);
    float d1 = __fadd_rn(__fsub_rn(x2n, 2.0f * a1), w2p[1]);
    float d2 = __fadd_rn(__fsub_rn(x2n, 2.0f * a2), w2p[2]);
    float d3 = __fadd_rn(__fsub_rn(x2n, 2.0f * a3), w2p[3]);
    // np.argmin: first occurrence of min == strict < in ascending k
    if (d0 < bestd) { bestd = d0; besti = kt + 0; }
    if (d1 < bestd) { bestd = d1; besti = kt + 1; }
    if (d2 < bestd) { bestd = d2; besti = kt + 2; }
    if (d3 < bestd) { bestd = d3; besti = kt + 3; }
  }
  idx[n] = besti;
  ilds[tid] = besti;
  __syncthreads();
  atomicAdd(&lc[besti], 1);

  // cooperative coalesced z_q gather: 256 rows x 16 float4
  const size_t zbase = (size_t)blockIdx.x * 256 * 16;
  float4* zq4 = (float4*)zq;
#pragma unroll
  for (int it = 0; it < 16; ++it) {
    int e = it * 256 + tid;
    int row = e >> 4;
    int col = e & 15;
    int kk = ilds[row];
    zq4[zbase + e] = w4[kk * 16 + col];
  }
  __syncthreads();
  for (int i = tid; i < KCB; i += 256) {
    int c = lc[i];
    if (c) atomicAdd(&counts[i], c);
  }
}

// --------------------------- scatter: per-block LDS partial sums (two d-halves)
__global__ __launch_bounds__(256) void scatter_partial(const float* __restrict__ x,
                                                       const int* __restrict__ idx,
                                                       float* __restrict__ psums) {
  __shared__ float ls[KCB * 32];  // 64 KiB
  const int tid = threadIdx.x;
  const int bid = blockIdx.x;               // 0..255
  const int rows_per_block = NROWS / 256;   // 1024
  const int r0 = bid * rows_per_block;
  const int rsub = tid >> 3;                // 0..31
  const int dq = tid & 7;                   // float4 quad within 32-col half
  for (int half = 0; half < 2; ++half) {
    for (int i = tid; i < KCB * 32; i += 256) ls[i] = 0.f;
    __syncthreads();
    for (int rr = 0; rr < rows_per_block; rr += 32) {
      int row = r0 + rr + rsub;
      int k = idx[row];
      float4 v = *(const float4*)(x + (size_t)row * DD + half * 32 + dq * 4);
      float* b = ls + k * 32;
      atomicAdd(&b[((dq * 4 + 0) + k) & 31], v.x);
      atomicAdd(&b[((dq * 4 + 1) + k) & 31], v.y);
      atomicAdd(&b[((dq * 4 + 2) + k) & 31], v.z);
      atomicAdd(&b[((dq * 4 + 3) + k) & 31], v.w);
    }
    __syncthreads();
    for (int i = tid; i < KCB * 32; i += 256) {
      int k = i >> 5, dl = i & 31;
      psums[(size_t)bid * (KCB * DD) + k * DD + half * 32 + dl] =
          ls[k * 32 + ((dl + k) & 31)];
    }
    __syncthreads();
  }
}

// ----------------------------- reduce partials -> mean -> dict_grad (float4)
__global__ __launch_bounds__(256) void reduce_dg(const float* __restrict__ psums,
                                                 const int* __restrict__ counts,
                                                 const float* __restrict__ w,
                                                 float* __restrict__ dg) {
  int e4 = blockIdx.x * 256 + threadIdx.x;  // < KCB*DD/4 = 8192
  int k = e4 >> 4;
  const float4* p4 = (const float4*)psums;
  float4 s = make_float4(0.f, 0.f, 0.f, 0.f);
  for (int p = 0; p < 256; ++p) {
    float4 v = p4[(size_t)p * (KCB * DD / 4) + e4];
    s.x = __fadd_rn(s.x, v.x); s.y = __fadd_rn(s.y, v.y);
    s.z = __fadd_rn(s.z, v.z); s.w = __fadd_rn(s.w, v.w);
  }
  int c = counts[k];
  float inv = 1.f / fmaxf((float)c, 1.f);
  float4 wv = ((const float4*)w)[e4];
  float4 o;
  o.x = (c > 0) ? (-2.0f * __fsub_rn(s.x * inv, wv.x)) : 0.f;
  o.y = (c > 0) ? (-2.0f * __fsub_rn(s.y * inv, wv.y)) : 0.f;
  o.z = (c > 0) ? (-2.0f * __fsub_rn(s.z * inv, wv.z)) : 0.f;
  o.w = (c > 0) ? (-2.0f * __fsub_rn(s.w * inv, wv.w)) : 0.f;
  ((float4*)dg)[e4] = o;
}

// ----------------------------- fallback path (small ws): global atomics
__global__ __launch_bounds__(256) void scatter_atomic(const float* __restrict__ x,
                                                      const int* __restrict__ idx,
                                                      float* __restrict__ sums) {
  int n = blockIdx.x * 256 + threadIdx.x;
  int k = idx[n];
  const float4* x4 = (const float4*)(x + (size_t)n * DD);
  float* s = sums + k * DD;
#pragma unroll
  for (int q = 0; q < 16; ++q) {
    float4 v = x4[q];
    atomicAdd(&s[4 * q + 0], v.x); atomicAdd(&s[4 * q + 1], v.y);
    atomicAdd(&s[4 * q + 2], v.z); atomicAdd(&s[4 * q + 3], v.w);
  }
}

__global__ __launch_bounds__(256) void dg_from_sums(const float* __restrict__ sums,
                                                    const int* __restrict__ counts,
                                                    const float* __restrict__ w,
                                                    float* __restrict__ dg) {
  int e = blockIdx.x * 256 + threadIdx.x;  // < KCB*DD
  int k = e >> 6;
  int c = counts[k];
  float mean = sums[e] / fmaxf((float)c, 1.f);
  dg[e] = (c > 0) ? (-2.0f * __fsub_rn(mean, w[e])) : 0.f;
}

extern "C" void kernel_launch(void* const* d_in, const int* in_sizes, int n_in,
                              void* d_out, int out_size, void* d_ws, size_t ws_size,
                              hipStream_t stream) {
  const float* x = (const float*)d_in[0];
  const float* w = (const float*)d_in[1];
  float* zq = (float*)d_out;
  float* dg = (float*)d_out + (size_t)NROWS * DD;

  char* ws = (char*)d_ws;
  int* idx = (int*)ws;                              // 1 MiB
  float* w2p = (float*)(ws + (1 << 20));            // 2 KiB (4 KiB pad)
  int* counts = (int*)(ws + (1 << 20) + 4096);      // 2 KiB (4 KiB pad)
  float* psums = (float*)(ws + (1 << 20) + 8192);   // 256*512*64*4 = 32 MiB
  const size_t need_partial =
      (size_t)(1 << 20) + 8192 + (size_t)256 * KCB * DD * sizeof(float);

  hipMemsetAsync(counts, 0, KCB * sizeof(int), stream);
  w2_kernel<<<1, 512, 0, stream>>>(w, w2p);
  vq_main<<<NROWS / 256, 256, 0, stream>>>(x, w, w2p, zq, idx, counts);

  if (ws_size >= need_partial) {
    scatter_partial<<<256, 256, 0, stream>>>(x, idx, psums);
    reduce_dg<<<KCB * DD / 4 / 256, 256, 0, stream>>>(psums, counts, w, dg);
  } else {
    float* sums = psums;  // 128 KiB, fits in the smaller footprint too
    hipMemsetAsync(sums, 0, KCB * DD * sizeof(float), stream);
    scatter_atomic<<<NROWS / 256, 256, 0, stream>>>(x, idx, sums);
    dg_from_sums<<<KCB * DD / 256, 256, 0, stream>>>(sums, counts, w, dg);
  }
}